// Round 13
// baseline (403.989 us; speedup 1.0000x reference)
//
#include <hip/hip_runtime.h>

// ---------------------------------------------------------------------------
// FDA_Module_21500606283969: out = x + MLP(LN(x))
// R3-R6: gelu_fast, XCD swizzle, xb residual, C^T epilogue.   [404.3 us]
// R9:    256^2 8-wave pipelined G1/G2.                        [398.3 us]
// R11:   chunk-ring deep pipeline.                            [399.0 us FLAT]
// R15:   7 -> 5 kernels: gemm23 (G2+G3 fused, h2 in LDS, -64MB HBM) +
//        prep_kernel (conv_all + u1c1 seed + ln_stats).
// R16:   no code change — resubmit after infra failure (R15 never executed).
//        gemm23 audited this round: stg WAR at phase boundaries (drain-
//        before-barrier), 2-bit/3-bit XOR writer-reader consistency, bank
//        counts (8 lanes/slot on all three tiles), index ranges, ws aliasing.
// ---------------------------------------------------------------------------

typedef short short8 __attribute__((ext_vector_type(8)));
typedef float floatx4 __attribute__((ext_vector_type(4)));
typedef unsigned short ushort4v __attribute__((ext_vector_type(4)));
typedef unsigned int uint2v __attribute__((ext_vector_type(2)));

__device__ __forceinline__ unsigned short f2bf(float f) {
    union { float f; unsigned int u; } a; a.f = f;
    unsigned int u = a.u;
    return (unsigned short)((u + 0x7FFFu + ((u >> 16) & 1u)) >> 16);
}

__device__ __forceinline__ float bf2f(unsigned short h) {
    union { unsigned int u; float f; } a; a.u = ((unsigned int)h) << 16;
    return a.f;
}

__device__ __forceinline__ unsigned int pkbf(float a, float b) {
    return (unsigned int)f2bf(a) | ((unsigned int)f2bf(b) << 16);
}

// tanh-approx GELU; |err vs exact erf-GELU| <~ 1e-4, below bf16 rounding.
__device__ __forceinline__ float gelu_fast(float v) {
    float u = 0.7978845608f * v * (1.0f + 0.044715f * v * v);
    float e = __builtin_amdgcn_exp2f(u * 2.885390082f);      // exp(2u)
    float t = 1.0f - 2.0f * __builtin_amdgcn_rcpf(1.0f + e); // tanh(u)
    return 0.5f * v * (1.0f + t);
}

// async global->LDS, 16B per lane; LDS dst = wave-uniform base + lane*16
__device__ __forceinline__ void gl_lds16(const unsigned short* g, unsigned short* l) {
    __builtin_amdgcn_global_load_lds(
        (const __attribute__((address_space(1))) void*)g,
        (__attribute__((address_space(3))) void*)l, 16, 0, 0);
}

#define BARX() asm volatile("s_barrier" ::: "memory")
#define VMW8() asm volatile("s_waitcnt vmcnt(8)" ::: "memory")
#define VMW4() asm volatile("s_waitcnt vmcnt(4)" ::: "memory")
#define VMW0() asm volatile("s_waitcnt vmcnt(0)" ::: "memory")

// ---- fused prep: weight transpose+convert (4608) + u1c1 seed (2) + LN (8192)
__global__ __launch_bounds__(256) void prep_kernel(
    const float* __restrict__ W1, const float* __restrict__ W2,
    const float* __restrict__ W3, const float* __restrict__ W4,
    const float* __restrict__ gamma, const float* __restrict__ b1,
    const float* __restrict__ x,
    unsigned short* __restrict__ Wt1, unsigned short* __restrict__ Wt2,
    unsigned short* __restrict__ Wt3, unsigned short* __restrict__ Wt4,
    float* __restrict__ u1, float* __restrict__ c1,
    float* __restrict__ mu, float* __restrict__ rs,
    unsigned short* __restrict__ xb) {
    int b = blockIdx.x;
    if (b < 4608) {            // ---- weight convert/transpose
        const float* W; unsigned short* Wt; int K, N; const float* sc = nullptr;
        if (b < 2048)      { W = W1; Wt = Wt1; K = 1024; N = 512;  sc = gamma; }
        else if (b < 3072) { W = W2; Wt = Wt2; K = 512;  N = 512;  b -= 2048; }
        else if (b < 3584) { W = W3; Wt = Wt3; K = 512;  N = 256;  b -= 3072; }
        else               { W = W4; Wt = Wt4; K = 256;  N = 1024; b -= 3584; }
        int t = b * 256 + threadIdx.x;
        int sh = 31 - __clz(N);
        int k = t >> sh, n = t & (N - 1);
        float v = W[t];
        if (sc) v *= sc[k];
        Wt[(size_t)n * K + k] = f2bf(v);
        return;
    }
    if (b < 4610) {            // ---- u1/c1 seed (before atomic u1c1_kernel)
        int n = (b - 4608) * 256 + threadIdx.x;
        u1[n] = 0.f;
        c1[n] = b1[n];
        return;
    }
    // ---- LN row stats + xb = bf16(x)
    const int D = 1024;
    int row = (b - 4610) * 4 + (threadIdx.x >> 6);
    int lane = threadIdx.x & 63;
    const float4* xr = (const float4*)(x + (size_t)row * D);
    float s = 0.f, ss = 0.f;
#pragma unroll
    for (int i = 0; i < 4; i++) {
        float4 v = xr[lane + 64 * i];
        s  += v.x + v.y + v.z + v.w;
        ss += v.x * v.x + v.y * v.y + v.z * v.z + v.w * v.w;
        if (xb) {
            ushort4v o;
            o.x = f2bf(v.x); o.y = f2bf(v.y); o.z = f2bf(v.z); o.w = f2bf(v.w);
            *(ushort4v*)(xb + (size_t)row * D + 4 * (lane + 64 * i)) = o;
        }
    }
#pragma unroll
    for (int off = 32; off; off >>= 1) {
        s  += __shfl_xor(s, off);
        ss += __shfl_xor(ss, off);
    }
    if (lane == 0) {
        float m = s * (1.0f / 1024.0f);
        mu[row] = m;
        rs[row] = rsqrtf(ss * (1.0f / 1024.0f) - m * m + 1e-5f);
    }
}

__global__ __launch_bounds__(256) void u1c1_kernel(
    const float* __restrict__ W1, const float* __restrict__ gamma,
    const float* __restrict__ beta, float* __restrict__ u1,
    float* __restrict__ c1) {
    const int N = 512;
    __shared__ float gs[16], bs[16];
    int n = threadIdx.x;
    int k0 = blockIdx.x * 16;
    if (n < 16) { gs[n] = gamma[k0 + n]; bs[n] = beta[k0 + n]; }
    __syncthreads();
    float ua = 0.f, ca = 0.f, ub = 0.f, cb = 0.f;
#pragma unroll
    for (int i = 0; i < 16; i++) {
        float w0 = W1[(size_t)(k0 + i) * N + n];
        float w1 = W1[(size_t)(k0 + i) * N + n + 256];
        ua += gs[i] * w0; ca += bs[i] * w0;
        ub += gs[i] * w1; cb += bs[i] * w1;
    }
    atomicAdd(&u1[n], ua);       atomicAdd(&c1[n], ca);
    atomicAdd(&u1[n + 256], ub); atomicAdd(&c1[n + 256], cb);
}

// ---------------------------------------------------------------------------
// 256x256 8-wave chunk-ring GEMM (G1, proven at R9/R11).
// ---------------------------------------------------------------------------
__device__ __forceinline__ void ldA8(const unsigned short* base, short8 (&a)[8]) {
#pragma unroll
    for (int mt = 0; mt < 8; mt++) a[mt] = *(const short8*)(base + mt * 512);
}
__device__ __forceinline__ void ldB2(const unsigned short* base, short8 (&bb)[2]) {
    bb[0] = *(const short8*)(base);
    bb[1] = *(const short8*)(base + 512);
}
template <int CH>
__device__ __forceinline__ void mm16(const short8 (&a)[8], const short8 (&bb)[2],
                                     floatx4 (&acc)[8][4]) {
    __builtin_amdgcn_s_setprio(1);
#pragma unroll
    for (int mt = 0; mt < 8; mt++)
#pragma unroll
        for (int nt = 0; nt < 2; nt++)
            acc[mt][CH * 2 + nt] = __builtin_amdgcn_mfma_f32_16x16x32_bf16(
                bb[nt], a[mt], acc[mt][CH * 2 + nt], 0, 0, 0);
    __builtin_amdgcn_s_setprio(0);
}

// MODE 0: steady | 1: penultimate | 2: last
template <int KLEN, int MODE>
__device__ __forceinline__ void do_tile(
    const unsigned short* aF0, const unsigned short* bF0,
    const unsigned short* aF1, const unsigned short* bF1,
    unsigned short* sA3, unsigned short* sB3,
    unsigned short* sA4, unsigned short* sB4,
    const unsigned short* gAs, const unsigned short* gBs,
    short8 (&a)[8], short8 (&bb)[2], floatx4 (&acc)[8][4]) {
    ldA8(aF0, a);
    ldB2(bF0, bb);
    if (MODE <= 1) {
        gl_lds16(gAs + 96, sA3);
        gl_lds16(gAs + 96 + (size_t)128 * KLEN, sA3 + 4096);
    }
    mm16<0>(a, bb, acc);
    BARX();
    ldB2(bF0 + 1024, bb);
    if (MODE <= 1) {
        gl_lds16(gBs + 96, sB3);
        gl_lds16(gBs + 96 + (size_t)128 * KLEN, sB3 + 4096);
    }
    mm16<1>(a, bb, acc);
    if (MODE <= 1) { VMW8(); } else { VMW0(); }
    BARX();
    ldA8(aF1, a);
    ldB2(bF1, bb);
    if (MODE == 0) {
        gl_lds16(gAs + 128, sA4);
        gl_lds16(gAs + 128 + (size_t)128 * KLEN, sA4 + 4096);
    }
    mm16<0>(a, bb, acc);
    BARX();
    ldB2(bF1 + 1024, bb);
    if (MODE == 0) {
        gl_lds16(gBs + 128, sB4);
        gl_lds16(gBs + 128 + (size_t)128 * KLEN, sB4 + 4096);
    }
    mm16<1>(a, bb, acc);
    if (MODE == 0) { VMW8(); }
    else if (MODE == 1) { VMW4(); }
    BARX();
}

template <int EPMODE, int NBN, int NT, int NOUT, int KLEN>
__global__ __launch_bounds__(512, 2) void gemm256_kernel(
    const unsigned short* __restrict__ A, const unsigned short* __restrict__ Bt,
    unsigned short* __restrict__ Out,
    const float* __restrict__ bias,
    const float* __restrict__ u1,
    const float* __restrict__ mu,
    const float* __restrict__ rs)
{
    __shared__ unsigned short lds[4][2][8192];

    const int tid  = threadIdx.x;
    const int wave = tid >> 6;
    const int lane = tid & 63;
    const int q    = lane >> 4;
    const int l16  = lane & 15;
    const int wm   = wave >> 2;
    const int wn   = wave & 3;

    const int id   = blockIdx.x;
    const int xcd  = id & 7;
    const int slot = id >> 3;
    const int m0   = (xcd + 8 * (slot / NBN)) * 256;
    const int n0   = (slot % NBN) * 256;

    const unsigned short* gAs = A  + (size_t)(m0 + (tid >> 2)) * KLEN + (tid & 3) * 8;
    const unsigned short* gBs = Bt + (size_t)(n0 + (tid >> 2)) * KLEN + (tid & 3) * 8;

    const int wo = wave << 9;
    unsigned short* sA[4]; unsigned short* sB[4];
    const unsigned short* fA[4]; const unsigned short* fB[4];
    const int aoff = (wm * 128 + l16) * 32 + q * 8;
    const int boff = (wn * 64 + l16) * 32 + q * 8;
#pragma unroll
    for (int s = 0; s < 4; s++) {
        sA[s] = &lds[s][0][0] + wo;
        sB[s] = &lds[s][1][0] + wo;
        fA[s] = &lds[s][0][0] + aoff;
        fB[s] = &lds[s][1][0] + boff;
    }

    floatx4 acc[8][4] = {};
    short8 a[8], bb[2];

    gl_lds16(gAs,      sA[0]); gl_lds16(gAs      + (size_t)128 * KLEN, sA[0] + 4096);
    gl_lds16(gBs,      sB[0]); gl_lds16(gBs      + (size_t)128 * KLEN, sB[0] + 4096);
    gl_lds16(gAs + 32, sA[1]); gl_lds16(gAs + 32 + (size_t)128 * KLEN, sA[1] + 4096);
    gl_lds16(gBs + 32, sB[1]); gl_lds16(gBs + 32 + (size_t)128 * KLEN, sB[1] + 4096);
    gl_lds16(gAs + 64, sA[2]); gl_lds16(gAs + 64 + (size_t)128 * KLEN, sA[2] + 4096);
    gl_lds16(gBs + 64, sB[2]); gl_lds16(gBs + 64 + (size_t)128 * KLEN, sB[2] + 4096);
    VMW8();
    BARX();

    for (int t = 0; t + 2 < NT; t += 2) {
        do_tile<KLEN, 0>(fA[0], fB[0], fA[1], fB[1], sA[3], sB[3], sA[0], sB[0],
                         gAs, gBs, a, bb, acc);
        gAs += 64; gBs += 64;
        do_tile<KLEN, 0>(fA[2], fB[2], fA[3], fB[3], sA[1], sB[1], sA[2], sB[2],
                         gAs, gBs, a, bb, acc);
        gAs += 64; gBs += 64;
    }
    do_tile<KLEN, 1>(fA[0], fB[0], fA[1], fB[1], sA[3], sB[3], sA[0], sB[0],
                     gAs, gBs, a, bb, acc);
    gAs += 64; gBs += 64;
    do_tile<KLEN, 2>(fA[2], fB[2], fA[3], fB[3], sA[1], sB[1], sA[2], sB[2],
                     gAs, gBs, a, bb, acc);

    float rs8[8], mu8[8];
    if constexpr (EPMODE == 0) {
#pragma unroll
        for (int ma = 0; ma < 8; ma++) {
            const int row = m0 + wm * 128 + ma * 16 + l16;
            rs8[ma] = rs[row];
            mu8[ma] = mu[row];
        }
    }
#pragma unroll
    for (int na = 0; na < 4; na++) {
        const int nb = n0 + wn * 64 + na * 16 + q * 4;
        const float4 bv = *(const float4*)(bias + nb);
        float4 uv = {0.f, 0.f, 0.f, 0.f};
        if constexpr (EPMODE == 0) uv = *(const float4*)(u1 + nb);
#pragma unroll
        for (int ma = 0; ma < 8; ma++) {
            const int row = m0 + wm * 128 + ma * 16 + l16;
            const size_t off = (size_t)row * NOUT + nb;
            float v0 = acc[ma][na][0], v1 = acc[ma][na][1];
            float v2 = acc[ma][na][2], v3 = acc[ma][na][3];
            if constexpr (EPMODE == 0) {
                v0 = gelu_fast(rs8[ma] * (v0 - mu8[ma] * uv.x) + bv.x);
                v1 = gelu_fast(rs8[ma] * (v1 - mu8[ma] * uv.y) + bv.y);
                v2 = gelu_fast(rs8[ma] * (v2 - mu8[ma] * uv.z) + bv.z);
                v3 = gelu_fast(rs8[ma] * (v3 - mu8[ma] * uv.w) + bv.w);
            } else {
                v0 = gelu_fast(v0 + bv.x);
                v1 = gelu_fast(v1 + bv.y);
                v2 = gelu_fast(v2 + bv.z);
                v3 = gelu_fast(v3 + bv.w);
            }
            uint2v o; o.x = pkbf(v0, v1); o.y = pkbf(v2, v3);
            *(uint2v*)(Out + off) = o;
        }
    }
}

// ---------------------------------------------------------------------------
// gemm23: h3 = gelu(gelu(h1*W2+b2)*W3+b3), h2-panel kept in LDS.
// Block = 128 rows, 512 thr / 8 waves (2m x 4n). LDS 144KB:
//   h2s 128x512 bf16 (col-granule 3-bit XOR swizzle; row stride 1KB),
//   stg 16KB: G2 {As[128][32] | Bs[128][32]} ; G3 Bs[256][32].
// ---------------------------------------------------------------------------
__global__ __launch_bounds__(512, 2) void gemm23_kernel(
    const unsigned short* __restrict__ h1, const unsigned short* __restrict__ Wt2,
    const unsigned short* __restrict__ Wt3, unsigned short* __restrict__ h3,
    const float* __restrict__ b2, const float* __restrict__ b3)
{
    __shared__ unsigned short h2s[65536];   // 128 KB
    __shared__ unsigned short stg[8192];    // 16 KB
    const int tid  = threadIdx.x;
    const int wave = tid >> 6, lane = tid & 63;
    const int q = lane >> 4, l16 = lane & 15;
    const int wm = wave >> 2, wn = wave & 3;        // 2 x 4 waves
    const int m0 = blockIdx.x * 128;
    const int sr2 = tid >> 2, pg2 = tid & 3;        // staging row / phys granule
    const int sg2 = pg2 ^ (sr2 & 3);                // inverse-swizzled src granule
    unsigned short* stW0 = stg + wave * 512;        // wave-uniform dst (lo 8KB)
    unsigned short* stW1 = stg + 4096 + wave * 512; // wave-uniform dst (hi 8KB)
    const int x2 = (q ^ (l16 & 3)) * 8;             // frag granule, 64B-row tiles

    floatx4 acc[4][4];
    short8 a[4], bb[4];

    // ---------------- G2 ----------------------------------------------------
    for (int nt4 = 0; nt4 < 4; nt4++) {
#pragma unroll
        for (int mt = 0; mt < 4; mt++)
#pragma unroll
            for (int nt = 0; nt < 2; nt++)
                acc[mt][nt] = (floatx4){0.f, 0.f, 0.f, 0.f};
        for (int ks = 0; ks < 16; ks++) {
            gl_lds16(h1  + (size_t)(m0 + sr2) * 512        + ks * 32 + sg2 * 8, stW0);
            gl_lds16(Wt2 + (size_t)(nt4 * 128 + sr2) * 512 + ks * 32 + sg2 * 8, stW1);
            __syncthreads();
#pragma unroll
            for (int mt = 0; mt < 4; mt++)
                a[mt] = *(const short8*)(stg + (wm * 64 + mt * 16 + l16) * 32 + x2);
#pragma unroll
            for (int nt = 0; nt < 2; nt++)
                bb[nt] = *(const short8*)(stg + 4096 + (wn * 32 + nt * 16 + l16) * 32 + x2);
#pragma unroll
            for (int mt = 0; mt < 4; mt++)
#pragma unroll
                for (int nt = 0; nt < 2; nt++)
                    acc[mt][nt] = __builtin_amdgcn_mfma_f32_16x16x32_bf16(
                        bb[nt], a[mt], acc[mt][nt], 0, 0, 0);
            __syncthreads();
        }
        // epilogue: gelu -> h2s (swizzled); ordered before G3 reads by the
        // next barrier (ds_writes drained by lgkmcnt at barrier).
#pragma unroll
        for (int nt = 0; nt < 2; nt++) {
            const int col = nt4 * 128 + wn * 32 + nt * 16 + q * 4;
            const float4 bv = *(const float4*)(b2 + col);
#pragma unroll
            for (int mt = 0; mt < 4; mt++) {
                const int row = wm * 64 + mt * 16 + l16;
                float v0 = gelu_fast(acc[mt][nt][0] + bv.x);
                float v1 = gelu_fast(acc[mt][nt][1] + bv.y);
                float v2 = gelu_fast(acc[mt][nt][2] + bv.z);
                float v3 = gelu_fast(acc[mt][nt][3] + bv.w);
                const int phys = (col >> 3) ^ (l16 & 7);
                uint2v o; o.x = pkbf(v0, v1); o.y = pkbf(v2, v3);
                *(uint2v*)(h2s + row * 512 + phys * 8 + (q & 1) * 4) = o;
            }
        }
    }

    // ---------------- G3 ----------------------------------------------------
#pragma unroll
    for (int mt = 0; mt < 4; mt++)
#pragma unroll
        for (int nt = 0; nt < 4; nt++)
            acc[mt][nt] = (floatx4){0.f, 0.f, 0.f, 0.f};
    for (int ks = 0; ks < 16; ks++) {
        // Bs3 [256][32]: rows 0-127 -> lo 8KB, rows 128-255 -> hi 8KB
        gl_lds16(Wt3 + (size_t)(sr2) * 512       + ks * 32 + sg2 * 8, stW0);
        gl_lds16(Wt3 + (size_t)(sr2 + 128) * 512 + ks * 32 + sg2 * 8, stW1);
        __syncthreads();
#pragma unroll
        for (int mt = 0; mt < 4; mt++) {
            const int row = wm * 64 + mt * 16 + l16;
            const int phys = (ks * 4 + q) ^ (l16 & 7);
            a[mt] = *(const short8*)(h2s + row * 512 + phys * 8);
        }
#pragma unroll
        for (int nt = 0; nt < 4; nt++)
            bb[nt] = *(const short8*)(stg + (wn * 64 + nt * 16 + l16) * 32 + x2);
#pragma unroll
        for (int mt = 0; mt < 4; mt++)
#pragma unroll
            for (int nt = 0; nt < 4; nt++)
                acc[mt][nt] = __builtin_amdgcn_mfma_f32_16x16x32_bf16(
                    bb[nt], a[mt], acc[mt][nt], 0, 0, 0);
        __syncthreads();
    }
    // epilogue -> h3 (M x 256 bf16)
#pragma unroll
    for (int nt = 0; nt < 4; nt++) {
        const int col = wn * 64 + nt * 16 + q * 4;
        const float4 bv = *(const float4*)(b3 + col);
#pragma unroll
        for (int mt = 0; mt < 4; mt++) {
            const int row = m0 + wm * 64 + mt * 16 + l16;
            float v0 = gelu_fast(acc[mt][nt][0] + bv.x);
            float v1 = gelu_fast(acc[mt][nt][1] + bv.y);
            float v2 = gelu_fast(acc[mt][nt][2] + bv.z);
            float v3 = gelu_fast(acc[mt][nt][3] + bv.w);
            uint2v o; o.x = pkbf(v0, v1); o.y = pkbf(v2, v3);
            *(uint2v*)(h3 + (size_t)row * 256 + col) = o;
        }
    }
}

// ---- 128x128 2-phase GEMM (G4 + AF32 fallback), proven -----------------
template <int EPMODE, bool AF32, int NBN, int NT_, int KT>
__global__ __launch_bounds__(256) void gemm_kernel(
    const void* __restrict__ Aptr, const unsigned short* __restrict__ Bt,
    void* __restrict__ Out,
    const float* __restrict__ bias,
    const float* __restrict__ u1,
    const float* __restrict__ mu,
    const float* __restrict__ rs,
    const void* __restrict__ resid)
{
    constexpr int BM = 128, BN = 128, BK = 64;
    constexpr int N = NT_, K = KT;
    __shared__ unsigned short As[BM][BK];
    __shared__ unsigned short Bs[BN][BK];

    const int tid  = threadIdx.x;
    const int wave = tid >> 6;
    const int lane = tid & 63;
    const int q    = lane >> 4;
    const int l16  = lane & 15;
    const int wm   = wave & 1;
    const int wn   = wave >> 1;

    const int id   = blockIdx.x;
    const int xcd  = id & 7;
    const int slot = id >> 3;
    const int m0   = (xcd + 8 * (slot / NBN)) * BM;
    const int n0   = (slot % NBN) * BN;

    const int sr  = tid >> 3;
    const int sc  = tid & 7;
    const int sg  = sc ^ (sr & 7);
    unsigned short* lA = &As[0][0] + (wave << 9);
    unsigned short* lB = &Bs[0][0] + (wave << 9);
    const unsigned short* gb0 = Bt + (size_t)(n0 + sr) * K + sg * 8;
    const unsigned short* ga0 = nullptr;
    if (!AF32) ga0 = (const unsigned short*)Aptr + (size_t)(m0 + sr) * K + sg * 8;

    floatx4 acc[4][4] = {};

#pragma unroll
    for (int k0 = 0; k0 < K; k0 += BK) {
        if (AF32) {
            const float* A = (const float*)Aptr;
            int c = tid & 15, r0 = tid >> 4;
#pragma unroll
            for (int i = 0; i < 8; i++) {
                int r = r0 + 16 * i;
                float4 v = *(const float4*)(A + (size_t)(m0 + r) * K + k0 + c * 4);
                ushort4v o;
                o.x = f2bf(v.x); o.y = f2bf(v.y);
                o.z = f2bf(v.z); o.w = f2bf(v.w);
                int idx = r * 64 + (((c >> 1) ^ (r & 7)) << 3) + ((c & 1) << 2);
                *(ushort4v*)(&As[0][0] + idx) = o;
            }
        } else {
#pragma unroll
            for (int c = 0; c < 4; c++)
                gl_lds16(ga0 + k0 + (size_t)(32 * c) * K, lA + c * 2048);
        }
#pragma unroll
        for (int c = 0; c < 4; c++)
            gl_lds16(gb0 + k0 + (size_t)(32 * c) * K, lB + c * 2048);
        __syncthreads();

#pragma unroll
        for (int kk = 0; kk < 2; kk++) {
            const int gsw = ((kk * 4 + q) ^ (l16 & 7)) * 8;
            short8 a[4], b[4];
#pragma unroll
            for (int mt = 0; mt < 4; mt++)
                a[mt] = *(const short8*)(&As[0][0] + (wm * 64 + mt * 16 + l16) * 64 + gsw);
#pragma unroll
            for (int nt = 0; nt < 4; nt++)
                b[nt] = *(const short8*)(&Bs[0][0] + (wn * 64 + nt * 16 + l16) * 64 + gsw);
#pragma unroll
            for (int nt = 0; nt < 4; nt++)
#pragma unroll
                for (int mt = 0; mt < 4; mt++)
                    acc[nt][mt] = __builtin_amdgcn_mfma_f32_16x16x32_bf16(
                        b[nt], a[mt], acc[nt][mt], 0, 0, 0);
        }
        __syncthreads();
    }

    float rs4[4], mu4[4];
    if constexpr (EPMODE == 0) {
#pragma unroll
        for (int mt = 0; mt < 4; mt++) {
            const int row = m0 + wm * 64 + mt * 16 + l16;
            rs4[mt] = rs[row];
            mu4[mt] = mu[row];
        }
    }
#pragma unroll
    for (int nt = 0; nt < 4; nt++) {
        const int nbase = n0 + wn * 64 + nt * 16 + q * 4;
        const float4 bv = *(const float4*)(bias + nbase);
        float4 uv = {0.f, 0.f, 0.f, 0.f};
        if constexpr (EPMODE == 0) uv = *(const float4*)(u1 + nbase);
#pragma unroll
        for (int mt = 0; mt < 4; mt++) {
            const int row = m0 + wm * 64 + mt * 16 + l16;
            const size_t off = (size_t)row * N + nbase;
            float v0 = acc[nt][mt][0], v1 = acc[nt][mt][1];
            float v2 = acc[nt][mt][2], v3 = acc[nt][mt][3];
            if constexpr (EPMODE == 0) {
                v0 = gelu_fast(rs4[mt] * (v0 - mu4[mt] * uv.x) + bv.x);
                v1 = gelu_fast(rs4[mt] * (v1 - mu4[mt] * uv.y) + bv.y);
                v2 = gelu_fast(rs4[mt] * (v2 - mu4[mt] * uv.z) + bv.z);
                v3 = gelu_fast(rs4[mt] * (v3 - mu4[mt] * uv.w) + bv.w);
                uint2v o; o.x = pkbf(v0, v1); o.y = pkbf(v2, v3);
                *(uint2v*)((unsigned short*)Out + off) = o;
            } else if constexpr (EPMODE == 1) {
                v0 = gelu_fast(v0 + bv.x);
                v1 = gelu_fast(v1 + bv.y);
                v2 = gelu_fast(v2 + bv.z);
                v3 = gelu_fast(v3 + bv.w);
                uint2v o; o.x = pkbf(v0, v1); o.y = pkbf(v2, v3);
                *(uint2v*)((unsigned short*)Out + off) = o;
            } else if constexpr (EPMODE == 2) {
                const float4 rv = *(const float4*)((const float*)resid + off);
                float4 o;
                o.x = v0 + bv.x + rv.x;
                o.y = v1 + bv.y + rv.y;
                o.z = v2 + bv.z + rv.z;
                o.w = v3 + bv.w + rv.w;
                *(float4*)((float*)Out + off) = o;
            } else {
                const ushort4v rv =
                    *(const ushort4v*)((const unsigned short*)resid + off);
                float4 o;
                o.x = v0 + bv.x + bf2f(rv.x);
                o.y = v1 + bv.y + bf2f(rv.y);
                o.z = v2 + bv.z + bf2f(rv.z);
                o.w = v3 + bv.w + bf2f(rv.w);
                *(float4*)((float*)Out + off) = o;
            }
        }
    }
}

extern "C" void kernel_launch(void* const* d_in, const int* in_sizes, int n_in,
                              void* d_out, int out_size, void* d_ws, size_t ws_size,
                              hipStream_t stream) {
    const float* x     = (const float*)d_in[0];
    const float* gamma = (const float*)d_in[1];
    const float* beta  = (const float*)d_in[2];
    const float* W1    = (const float*)d_in[3];
    const float* b1    = (const float*)d_in[4];
    const float* W2    = (const float*)d_in[5];
    const float* b2    = (const float*)d_in[6];
    const float* W3    = (const float*)d_in[7];
    const float* b3    = (const float*)d_in[8];
    const float* W4    = (const float*)d_in[9];
    const float* b4    = (const float*)d_in[10];
    float* out = (float*)d_out;

    const int D = 1024, H1 = 512, H2 = 512;
    const int M = in_sizes[0] / D;   // 32768

    char* ws = (char*)d_ws;
    unsigned short* Wt1 = (unsigned short*)(ws + 0);
    unsigned short* Wt2 = (unsigned short*)(ws + 1048576);
    unsigned short* Wt3 = (unsigned short*)(ws + 1572864);
    unsigned short* Wt4 = (unsigned short*)(ws + 1835008);
    float* u1           = (float*)(ws + 2359296);
    float* c1           = (float*)(ws + 2361344);
    float* muv          = (float*)(ws + 2363392);
    float* rsv          = (float*)(ws + 2494464);
    unsigned short* h1  = (unsigned short*)(ws + 2625536);    // M x 512 bf16
    unsigned short* h3  = (unsigned short*)(ws + 36179968);   // M x 256 bf16 (old h2 slot)
    size_t base_end     = 36179968 + (size_t)M * H2 * 2;
    unsigned short* xb  = (unsigned short*)(ws + base_end);
    bool use_xb = (ws_size >= base_end + (size_t)M * D * 2);

    const int NBM = M / 128;   // 256

    // 1) prep: weight convert + u1c1 seed + LN stats (+xb)
    prep_kernel<<<4610 + M / 4, 256, 0, stream>>>(
        W1, W2, W3, W4, gamma, b1, x, Wt1, Wt2, Wt3, Wt4,
        u1, c1, muv, rsv, use_xb ? xb : nullptr);
    // 2) u1/c1 accumulation
    u1c1_kernel<<<D / 16, 256, 0, stream>>>(W1, gamma, beta, u1, c1);
    // 3) G1
    if (use_xb) {
        gemm256_kernel<0, 2, 16, 512, 1024><<<(M / 256) * 2, 512, 0, stream>>>(
            xb, Wt1, h1, c1, u1, muv, rsv);
    } else {
        gemm_kernel<0, true, 4, 512, 1024><<<4 * NBM, 256, 0, stream>>>(
            x, Wt1, h1, c1, u1, muv, rsv, nullptr);
    }
    // 4) G2+G3 fused (h2 stays in LDS)
    gemm23_kernel<<<M / 128, 512, 0, stream>>>(h1, Wt2, Wt3, h3, b2, b3);
    // 5) G4 (+residual)
    if (use_xb) {
        gemm_kernel<3, false, 8, 1024, 256><<<8 * NBM, 256, 0, stream>>>(
            h3, Wt4, out, b4, nullptr, nullptr, nullptr, xb);
    } else {
        gemm_kernel<2, false, 8, 1024, 256><<<8 * NBM, 256, 0, stream>>>(
            h3, Wt4, out, b4, nullptr, nullptr, nullptr, x);
    }
}

// Round 14
// 401.942 us; speedup vs baseline: 1.0051x; 1.0051x over previous
//
#include <hip/hip_runtime.h>

// ---------------------------------------------------------------------------
// FDA_Module_21500606283969: out = x + MLP(LN(x))
// Measured: R7=404.3 | R9=398.3 | R11=399.0 | R15=404.0 — all within the
// +-1.5% noise band; ~158us of the metric matches 2x512MB harness fills.
// R17: attribution-clean best-of-both: R11's measured-best GEMM chain
//      (G1/G2 = chunk-ring gemm256; G3/G4 = proven 128^2 2-phase) + R15's
//      fused prep (conv_all + u1c1 seed + ln_stats in one launch; 6 total).
//      gemm23 dropped (its naive G2 loop likely cost the +5 at R15).
// ---------------------------------------------------------------------------

typedef short short8 __attribute__((ext_vector_type(8)));
typedef float floatx4 __attribute__((ext_vector_type(4)));
typedef unsigned short ushort4v __attribute__((ext_vector_type(4)));
typedef unsigned int uint2v __attribute__((ext_vector_type(2)));

__device__ __forceinline__ unsigned short f2bf(float f) {
    union { float f; unsigned int u; } a; a.f = f;
    unsigned int u = a.u;
    return (unsigned short)((u + 0x7FFFu + ((u >> 16) & 1u)) >> 16);
}

__device__ __forceinline__ float bf2f(unsigned short h) {
    union { unsigned int u; float f; } a; a.u = ((unsigned int)h) << 16;
    return a.f;
}

__device__ __forceinline__ unsigned int pkbf(float a, float b) {
    return (unsigned int)f2bf(a) | ((unsigned int)f2bf(b) << 16);
}

// tanh-approx GELU; |err vs exact erf-GELU| <~ 1e-4, below bf16 rounding.
__device__ __forceinline__ float gelu_fast(float v) {
    float u = 0.7978845608f * v * (1.0f + 0.044715f * v * v);
    float e = __builtin_amdgcn_exp2f(u * 2.885390082f);      // exp(2u)
    float t = 1.0f - 2.0f * __builtin_amdgcn_rcpf(1.0f + e); // tanh(u)
    return 0.5f * v * (1.0f + t);
}

// async global->LDS, 16B per lane; LDS dst = wave-uniform base + lane*16
__device__ __forceinline__ void gl_lds16(const unsigned short* g, unsigned short* l) {
    __builtin_amdgcn_global_load_lds(
        (const __attribute__((address_space(1))) void*)g,
        (__attribute__((address_space(3))) void*)l, 16, 0, 0);
}

#define BARX() asm volatile("s_barrier" ::: "memory")
#define VMW8() asm volatile("s_waitcnt vmcnt(8)" ::: "memory")
#define VMW4() asm volatile("s_waitcnt vmcnt(4)" ::: "memory")
#define VMW0() asm volatile("s_waitcnt vmcnt(0)" ::: "memory")

// ---- fused prep: weight transpose+convert (4608) + u1c1 seed (2) + LN (8192)
__global__ __launch_bounds__(256) void prep_kernel(
    const float* __restrict__ W1, const float* __restrict__ W2,
    const float* __restrict__ W3, const float* __restrict__ W4,
    const float* __restrict__ gamma, const float* __restrict__ b1,
    const float* __restrict__ x,
    unsigned short* __restrict__ Wt1, unsigned short* __restrict__ Wt2,
    unsigned short* __restrict__ Wt3, unsigned short* __restrict__ Wt4,
    float* __restrict__ u1, float* __restrict__ c1,
    float* __restrict__ mu, float* __restrict__ rs,
    unsigned short* __restrict__ xb) {
    int b = blockIdx.x;
    if (b < 4608) {            // ---- weight convert/transpose
        const float* W; unsigned short* Wt; int K, N; const float* sc = nullptr;
        if (b < 2048)      { W = W1; Wt = Wt1; K = 1024; N = 512;  sc = gamma; }
        else if (b < 3072) { W = W2; Wt = Wt2; K = 512;  N = 512;  b -= 2048; }
        else if (b < 3584) { W = W3; Wt = Wt3; K = 512;  N = 256;  b -= 3072; }
        else               { W = W4; Wt = Wt4; K = 256;  N = 1024; b -= 3584; }
        int t = b * 256 + threadIdx.x;
        int sh = 31 - __clz(N);
        int k = t >> sh, n = t & (N - 1);
        float v = W[t];
        if (sc) v *= sc[k];
        Wt[(size_t)n * K + k] = f2bf(v);
        return;
    }
    if (b < 4610) {            // ---- u1/c1 seed (before atomic u1c1_kernel)
        int n = (b - 4608) * 256 + threadIdx.x;
        u1[n] = 0.f;
        c1[n] = b1[n];
        return;
    }
    // ---- LN row stats + xb = bf16(x)
    const int D = 1024;
    int row = (b - 4610) * 4 + (threadIdx.x >> 6);
    int lane = threadIdx.x & 63;
    const float4* xr = (const float4*)(x + (size_t)row * D);
    float s = 0.f, ss = 0.f;
#pragma unroll
    for (int i = 0; i < 4; i++) {
        float4 v = xr[lane + 64 * i];
        s  += v.x + v.y + v.z + v.w;
        ss += v.x * v.x + v.y * v.y + v.z * v.z + v.w * v.w;
        if (xb) {
            ushort4v o;
            o.x = f2bf(v.x); o.y = f2bf(v.y); o.z = f2bf(v.z); o.w = f2bf(v.w);
            *(ushort4v*)(xb + (size_t)row * D + 4 * (lane + 64 * i)) = o;
        }
    }
#pragma unroll
    for (int off = 32; off; off >>= 1) {
        s  += __shfl_xor(s, off);
        ss += __shfl_xor(ss, off);
    }
    if (lane == 0) {
        float m = s * (1.0f / 1024.0f);
        mu[row] = m;
        rs[row] = rsqrtf(ss * (1.0f / 1024.0f) - m * m + 1e-5f);
    }
}

__global__ __launch_bounds__(256) void u1c1_kernel(
    const float* __restrict__ W1, const float* __restrict__ gamma,
    const float* __restrict__ beta, float* __restrict__ u1,
    float* __restrict__ c1) {
    const int N = 512;
    __shared__ float gs[16], bs[16];
    int n = threadIdx.x;
    int k0 = blockIdx.x * 16;
    if (n < 16) { gs[n] = gamma[k0 + n]; bs[n] = beta[k0 + n]; }
    __syncthreads();
    float ua = 0.f, ca = 0.f, ub = 0.f, cb = 0.f;
#pragma unroll
    for (int i = 0; i < 16; i++) {
        float w0 = W1[(size_t)(k0 + i) * N + n];
        float w1 = W1[(size_t)(k0 + i) * N + n + 256];
        ua += gs[i] * w0; ca += bs[i] * w0;
        ub += gs[i] * w1; cb += bs[i] * w1;
    }
    atomicAdd(&u1[n], ua);       atomicAdd(&c1[n], ca);
    atomicAdd(&u1[n + 256], ub); atomicAdd(&c1[n + 256], cb);
}

// ---------------------------------------------------------------------------
// 256x256 8-wave chunk-ring GEMM (G1/G2, measured at R11).
// ---------------------------------------------------------------------------
__device__ __forceinline__ void ldA8(const unsigned short* base, short8 (&a)[8]) {
#pragma unroll
    for (int mt = 0; mt < 8; mt++) a[mt] = *(const short8*)(base + mt * 512);
}
__device__ __forceinline__ void ldB2(const unsigned short* base, short8 (&bb)[2]) {
    bb[0] = *(const short8*)(base);
    bb[1] = *(const short8*)(base + 512);
}
template <int CH>
__device__ __forceinline__ void mm16(const short8 (&a)[8], const short8 (&bb)[2],
                                     floatx4 (&acc)[8][4]) {
    __builtin_amdgcn_s_setprio(1);
#pragma unroll
    for (int mt = 0; mt < 8; mt++)
#pragma unroll
        for (int nt = 0; nt < 2; nt++)
            acc[mt][CH * 2 + nt] = __builtin_amdgcn_mfma_f32_16x16x32_bf16(
                bb[nt], a[mt], acc[mt][CH * 2 + nt], 0, 0, 0);
    __builtin_amdgcn_s_setprio(0);
}

// MODE 0: steady | 1: penultimate | 2: last
template <int KLEN, int MODE>
__device__ __forceinline__ void do_tile(
    const unsigned short* aF0, const unsigned short* bF0,
    const unsigned short* aF1, const unsigned short* bF1,
    unsigned short* sA3, unsigned short* sB3,
    unsigned short* sA4, unsigned short* sB4,
    const unsigned short* gAs, const unsigned short* gBs,
    short8 (&a)[8], short8 (&bb)[2], floatx4 (&acc)[8][4]) {
    ldA8(aF0, a);
    ldB2(bF0, bb);
    if (MODE <= 1) {
        gl_lds16(gAs + 96, sA3);
        gl_lds16(gAs + 96 + (size_t)128 * KLEN, sA3 + 4096);
    }
    mm16<0>(a, bb, acc);
    BARX();
    ldB2(bF0 + 1024, bb);
    if (MODE <= 1) {
        gl_lds16(gBs + 96, sB3);
        gl_lds16(gBs + 96 + (size_t)128 * KLEN, sB3 + 4096);
    }
    mm16<1>(a, bb, acc);
    if (MODE <= 1) { VMW8(); } else { VMW0(); }
    BARX();
    ldA8(aF1, a);
    ldB2(bF1, bb);
    if (MODE == 0) {
        gl_lds16(gAs + 128, sA4);
        gl_lds16(gAs + 128 + (size_t)128 * KLEN, sA4 + 4096);
    }
    mm16<0>(a, bb, acc);
    BARX();
    ldB2(bF1 + 1024, bb);
    if (MODE == 0) {
        gl_lds16(gBs + 128, sB4);
        gl_lds16(gBs + 128 + (size_t)128 * KLEN, sB4 + 4096);
    }
    mm16<1>(a, bb, acc);
    if (MODE == 0) { VMW8(); }
    else if (MODE == 1) { VMW4(); }
    BARX();
}

template <int EPMODE, int NBN, int NT, int NOUT, int KLEN>
__global__ __launch_bounds__(512, 2) void gemm256_kernel(
    const unsigned short* __restrict__ A, const unsigned short* __restrict__ Bt,
    unsigned short* __restrict__ Out,
    const float* __restrict__ bias,
    const float* __restrict__ u1,
    const float* __restrict__ mu,
    const float* __restrict__ rs)
{
    __shared__ unsigned short lds[4][2][8192];

    const int tid  = threadIdx.x;
    const int wave = tid >> 6;
    const int lane = tid & 63;
    const int q    = lane >> 4;
    const int l16  = lane & 15;
    const int wm   = wave >> 2;
    const int wn   = wave & 3;

    const int id   = blockIdx.x;
    const int xcd  = id & 7;
    const int slot = id >> 3;
    const int m0   = (xcd + 8 * (slot / NBN)) * 256;
    const int n0   = (slot % NBN) * 256;

    const unsigned short* gAs = A  + (size_t)(m0 + (tid >> 2)) * KLEN + (tid & 3) * 8;
    const unsigned short* gBs = Bt + (size_t)(n0 + (tid >> 2)) * KLEN + (tid & 3) * 8;

    const int wo = wave << 9;
    unsigned short* sA[4]; unsigned short* sB[4];
    const unsigned short* fA[4]; const unsigned short* fB[4];
    const int aoff = (wm * 128 + l16) * 32 + q * 8;
    const int boff = (wn * 64 + l16) * 32 + q * 8;
#pragma unroll
    for (int s = 0; s < 4; s++) {
        sA[s] = &lds[s][0][0] + wo;
        sB[s] = &lds[s][1][0] + wo;
        fA[s] = &lds[s][0][0] + aoff;
        fB[s] = &lds[s][1][0] + boff;
    }

    floatx4 acc[8][4] = {};
    short8 a[8], bb[2];

    gl_lds16(gAs,      sA[0]); gl_lds16(gAs      + (size_t)128 * KLEN, sA[0] + 4096);
    gl_lds16(gBs,      sB[0]); gl_lds16(gBs      + (size_t)128 * KLEN, sB[0] + 4096);
    gl_lds16(gAs + 32, sA[1]); gl_lds16(gAs + 32 + (size_t)128 * KLEN, sA[1] + 4096);
    gl_lds16(gBs + 32, sB[1]); gl_lds16(gBs + 32 + (size_t)128 * KLEN, sB[1] + 4096);
    gl_lds16(gAs + 64, sA[2]); gl_lds16(gAs + 64 + (size_t)128 * KLEN, sA[2] + 4096);
    gl_lds16(gBs + 64, sB[2]); gl_lds16(gBs + 64 + (size_t)128 * KLEN, sB[2] + 4096);
    VMW8();
    BARX();

    for (int t = 0; t + 2 < NT; t += 2) {
        do_tile<KLEN, 0>(fA[0], fB[0], fA[1], fB[1], sA[3], sB[3], sA[0], sB[0],
                         gAs, gBs, a, bb, acc);
        gAs += 64; gBs += 64;
        do_tile<KLEN, 0>(fA[2], fB[2], fA[3], fB[3], sA[1], sB[1], sA[2], sB[2],
                         gAs, gBs, a, bb, acc);
        gAs += 64; gBs += 64;
    }
    do_tile<KLEN, 1>(fA[0], fB[0], fA[1], fB[1], sA[3], sB[3], sA[0], sB[0],
                     gAs, gBs, a, bb, acc);
    gAs += 64; gBs += 64;
    do_tile<KLEN, 2>(fA[2], fB[2], fA[3], fB[3], sA[1], sB[1], sA[2], sB[2],
                     gAs, gBs, a, bb, acc);

    float rs8[8], mu8[8];
    if constexpr (EPMODE == 0) {
#pragma unroll
        for (int ma = 0; ma < 8; ma++) {
            const int row = m0 + wm * 128 + ma * 16 + l16;
            rs8[ma] = rs[row];
            mu8[ma] = mu[row];
        }
    }
#pragma unroll
    for (int na = 0; na < 4; na++) {
        const int nb = n0 + wn * 64 + na * 16 + q * 4;
        const float4 bv = *(const float4*)(bias + nb);
        float4 uv = {0.f, 0.f, 0.f, 0.f};
        if constexpr (EPMODE == 0) uv = *(const float4*)(u1 + nb);
#pragma unroll
        for (int ma = 0; ma < 8; ma++) {
            const int row = m0 + wm * 128 + ma * 16 + l16;
            const size_t off = (size_t)row * NOUT + nb;
            float v0 = acc[ma][na][0], v1 = acc[ma][na][1];
            float v2 = acc[ma][na][2], v3 = acc[ma][na][3];
            if constexpr (EPMODE == 0) {
                v0 = gelu_fast(rs8[ma] * (v0 - mu8[ma] * uv.x) + bv.x);
                v1 = gelu_fast(rs8[ma] * (v1 - mu8[ma] * uv.y) + bv.y);
                v2 = gelu_fast(rs8[ma] * (v2 - mu8[ma] * uv.z) + bv.z);
                v3 = gelu_fast(rs8[ma] * (v3 - mu8[ma] * uv.w) + bv.w);
            } else {
                v0 = gelu_fast(v0 + bv.x);
                v1 = gelu_fast(v1 + bv.y);
                v2 = gelu_fast(v2 + bv.z);
                v3 = gelu_fast(v3 + bv.w);
            }
            uint2v o; o.x = pkbf(v0, v1); o.y = pkbf(v2, v3);
            *(uint2v*)(Out + off) = o;
        }
    }
}

// ---- 128x128 2-phase GEMM (G3/G4), measured at R7/R9/R11 ----------------
template <int EPMODE, bool AF32, int NBN, int NT_, int KT>
__global__ __launch_bounds__(256) void gemm_kernel(
    const void* __restrict__ Aptr, const unsigned short* __restrict__ Bt,
    void* __restrict__ Out,
    const float* __restrict__ bias,
    const float* __restrict__ u1,
    const float* __restrict__ mu,
    const float* __restrict__ rs,
    const void* __restrict__ resid)
{
    constexpr int BM = 128, BN = 128, BK = 64;
    constexpr int N = NT_, K = KT;
    __shared__ unsigned short As[BM][BK];
    __shared__ unsigned short Bs[BN][BK];

    const int tid  = threadIdx.x;
    const int wave = tid >> 6;
    const int lane = tid & 63;
    const int q    = lane >> 4;
    const int l16  = lane & 15;
    const int wm   = wave & 1;
    const int wn   = wave >> 1;

    const int id   = blockIdx.x;
    const int xcd  = id & 7;
    const int slot = id >> 3;
    const int m0   = (xcd + 8 * (slot / NBN)) * BM;
    const int n0   = (slot % NBN) * BN;

    const int sr  = tid >> 3;
    const int sc  = tid & 7;
    const int sg  = sc ^ (sr & 7);
    unsigned short* lA = &As[0][0] + (wave << 9);
    unsigned short* lB = &Bs[0][0] + (wave << 9);
    const unsigned short* gb0 = Bt + (size_t)(n0 + sr) * K + sg * 8;
    const unsigned short* ga0 = nullptr;
    if (!AF32) ga0 = (const unsigned short*)Aptr + (size_t)(m0 + sr) * K + sg * 8;

    floatx4 acc[4][4] = {};

#pragma unroll
    for (int k0 = 0; k0 < K; k0 += BK) {
        if (AF32) {
            const float* A = (const float*)Aptr;
            int c = tid & 15, r0 = tid >> 4;
#pragma unroll
            for (int i = 0; i < 8; i++) {
                int r = r0 + 16 * i;
                float4 v = *(const float4*)(A + (size_t)(m0 + r) * K + k0 + c * 4);
                ushort4v o;
                o.x = f2bf(v.x); o.y = f2bf(v.y);
                o.z = f2bf(v.z); o.w = f2bf(v.w);
                int idx = r * 64 + (((c >> 1) ^ (r & 7)) << 3) + ((c & 1) << 2);
                *(ushort4v*)(&As[0][0] + idx) = o;
            }
        } else {
#pragma unroll
            for (int c = 0; c < 4; c++)
                gl_lds16(ga0 + k0 + (size_t)(32 * c) * K, lA + c * 2048);
        }
#pragma unroll
        for (int c = 0; c < 4; c++)
            gl_lds16(gb0 + k0 + (size_t)(32 * c) * K, lB + c * 2048);
        __syncthreads();

#pragma unroll
        for (int kk = 0; kk < 2; kk++) {
            const int gsw = ((kk * 4 + q) ^ (l16 & 7)) * 8;
            short8 a[4], b[4];
#pragma unroll
            for (int mt = 0; mt < 4; mt++)
                a[mt] = *(const short8*)(&As[0][0] + (wm * 64 + mt * 16 + l16) * 64 + gsw);
#pragma unroll
            for (int nt = 0; nt < 4; nt++)
                b[nt] = *(const short8*)(&Bs[0][0] + (wn * 64 + nt * 16 + l16) * 64 + gsw);
#pragma unroll
            for (int nt = 0; nt < 4; nt++)
#pragma unroll
                for (int mt = 0; mt < 4; mt++)
                    acc[nt][mt] = __builtin_amdgcn_mfma_f32_16x16x32_bf16(
                        b[nt], a[mt], acc[nt][mt], 0, 0, 0);
        }
        __syncthreads();
    }

    float rs4[4], mu4[4];
    if constexpr (EPMODE == 0) {
#pragma unroll
        for (int mt = 0; mt < 4; mt++) {
            const int row = m0 + wm * 64 + mt * 16 + l16;
            rs4[mt] = rs[row];
            mu4[mt] = mu[row];
        }
    }
#pragma unroll
    for (int nt = 0; nt < 4; nt++) {
        const int nbase = n0 + wn * 64 + nt * 16 + q * 4;
        const float4 bv = *(const float4*)(bias + nbase);
        float4 uv = {0.f, 0.f, 0.f, 0.f};
        if constexpr (EPMODE == 0) uv = *(const float4*)(u1 + nbase);
#pragma unroll
        for (int mt = 0; mt < 4; mt++) {
            const int row = m0 + wm * 64 + mt * 16 + l16;
            const size_t off = (size_t)row * N + nbase;
            float v0 = acc[nt][mt][0], v1 = acc[nt][mt][1];
            float v2 = acc[nt][mt][2], v3 = acc[nt][mt][3];
            if constexpr (EPMODE == 0) {
                v0 = gelu_fast(rs4[mt] * (v0 - mu4[mt] * uv.x) + bv.x);
                v1 = gelu_fast(rs4[mt] * (v1 - mu4[mt] * uv.y) + bv.y);
                v2 = gelu_fast(rs4[mt] * (v2 - mu4[mt] * uv.z) + bv.z);
                v3 = gelu_fast(rs4[mt] * (v3 - mu4[mt] * uv.w) + bv.w);
                uint2v o; o.x = pkbf(v0, v1); o.y = pkbf(v2, v3);
                *(uint2v*)((unsigned short*)Out + off) = o;
            } else if constexpr (EPMODE == 1) {
                v0 = gelu_fast(v0 + bv.x);
                v1 = gelu_fast(v1 + bv.y);
                v2 = gelu_fast(v2 + bv.z);
                v3 = gelu_fast(v3 + bv.w);
                uint2v o; o.x = pkbf(v0, v1); o.y = pkbf(v2, v3);
                *(uint2v*)((unsigned short*)Out + off) = o;
            } else if constexpr (EPMODE == 2) {
                const float4 rv = *(const float4*)((const float*)resid + off);
                float4 o;
                o.x = v0 + bv.x + rv.x;
                o.y = v1 + bv.y + rv.y;
                o.z = v2 + bv.z + rv.z;
                o.w = v3 + bv.w + rv.w;
                *(float4*)((float*)Out + off) = o;
            } else {
                const ushort4v rv =
                    *(const ushort4v*)((const unsigned short*)resid + off);
                float4 o;
                o.x = v0 + bv.x + bf2f(rv.x);
                o.y = v1 + bv.y + bf2f(rv.y);
                o.z = v2 + bv.z + bf2f(rv.z);
                o.w = v3 + bv.w + bf2f(rv.w);
                *(float4*)((float*)Out + off) = o;
            }
        }
    }
}

extern "C" void kernel_launch(void* const* d_in, const int* in_sizes, int n_in,
                              void* d_out, int out_size, void* d_ws, size_t ws_size,
                              hipStream_t stream) {
    const float* x     = (const float*)d_in[0];
    const float* gamma = (const float*)d_in[1];
    const float* beta  = (const float*)d_in[2];
    const float* W1    = (const float*)d_in[3];
    const float* b1    = (const float*)d_in[4];
    const float* W2    = (const float*)d_in[5];
    const float* b2    = (const float*)d_in[6];
    const float* W3    = (const float*)d_in[7];
    const float* b3    = (const float*)d_in[8];
    const float* W4    = (const float*)d_in[9];
    const float* b4    = (const float*)d_in[10];
    float* out = (float*)d_out;

    const int D = 1024, H1 = 512, H2 = 512;
    const int M = in_sizes[0] / D;   // 32768

    char* ws = (char*)d_ws;
    unsigned short* Wt1 = (unsigned short*)(ws + 0);
    unsigned short* Wt2 = (unsigned short*)(ws + 1048576);
    unsigned short* Wt3 = (unsigned short*)(ws + 1572864);
    unsigned short* Wt4 = (unsigned short*)(ws + 1835008);
    float* u1           = (float*)(ws + 2359296);
    float* c1           = (float*)(ws + 2361344);
    float* muv          = (float*)(ws + 2363392);
    float* rsv          = (float*)(ws + 2494464);
    unsigned short* h1  = (unsigned short*)(ws + 2625536);    // M x 512 bf16
    unsigned short* h2  = (unsigned short*)(ws + 36179968);   // M x 512 bf16
    unsigned short* h3  = h1;                                 // h1 dead after G2
    size_t base_end     = 36179968 + (size_t)M * H2 * 2;
    unsigned short* xb  = (unsigned short*)(ws + base_end);
    bool use_xb = (ws_size >= base_end + (size_t)M * D * 2);

    const int NBM = M / 128;   // 256

    // 1) prep: weight convert + u1c1 seed + LN stats (+xb)
    prep_kernel<<<4610 + M / 4, 256, 0, stream>>>(
        W1, W2, W3, W4, gamma, b1, x, Wt1, Wt2, Wt3, Wt4,
        u1, c1, muv, rsv, use_xb ? xb : nullptr);
    // 2) u1/c1 accumulation
    u1c1_kernel<<<D / 16, 256, 0, stream>>>(W1, gamma, beta, u1, c1);
    // 3) G1
    if (use_xb) {
        gemm256_kernel<0, 2, 16, 512, 1024><<<(M / 256) * 2, 512, 0, stream>>>(
            xb, Wt1, h1, c1, u1, muv, rsv);
    } else {
        gemm_kernel<0, true, 4, 512, 1024><<<4 * NBM, 256, 0, stream>>>(
            x, Wt1, h1, c1, u1, muv, rsv, nullptr);
    }
    // 4) G2
    gemm256_kernel<1, 2, 8, 512, 512><<<(M / 256) * 2, 512, 0, stream>>>(
        h1, Wt2, h2, b2, nullptr, nullptr, nullptr);
    // 5) G3
    gemm_kernel<1, false, 2, 256, 512><<<2 * NBM, 256, 0, stream>>>(
        h2, Wt3, h3, b3, nullptr, nullptr, nullptr, nullptr);
    // 6) G4 (+residual)
    if (use_xb) {
        gemm_kernel<3, false, 8, 1024, 256><<<8 * NBM, 256, 0, stream>>>(
            h3, Wt4, out, b4, nullptr, nullptr, nullptr, xb);
    } else {
        gemm_kernel<2, false, 8, 1024, 256><<<8 * NBM, 256, 0, stream>>>(
            h3, Wt4, out, b4, nullptr, nullptr, nullptr, x);
    }
}

// Round 15
// 392.708 us; speedup vs baseline: 1.0287x; 1.0235x over previous
//
#include <hip/hip_runtime.h>

// ---------------------------------------------------------------------------
// FDA_Module_21500606283969: out = x + MLP(LN(x))
// Measured: R7=404.3 | R9=398.3 | R11=399.0 | R15=404.0 | R17=401.9.
// R17 profile (first gemm256 counters): G1 = 89.5us, MfmaUtil 15%,
// SQ_LDS_BANK_CONFLICT 3.15M, occupancy 21%, HBM 16% -> LDS/latency-bound.
// R18: fix the conflict. [256][32] 64B-stride chunks: bank = 16*(row&1)+4*g;
//      a 16-lane phase with unswizzled g=q hits ONE granule -> 8-way.
//      Swizzle phys_g = logical_g ^ ((row>>1)&3): quarter-wave covers all
//      8 (half,granule) positions 2 lanes each = conflict-free. Applied to
//      staged source (linear LDS dest preserved) + frag reads. The 128^2
//      kernel's 128B-stride 3-bit XOR is already free (checked) - unchanged.
// ---------------------------------------------------------------------------

typedef short short8 __attribute__((ext_vector_type(8)));
typedef float floatx4 __attribute__((ext_vector_type(4)));
typedef unsigned short ushort4v __attribute__((ext_vector_type(4)));
typedef unsigned int uint2v __attribute__((ext_vector_type(2)));

__device__ __forceinline__ unsigned short f2bf(float f) {
    union { float f; unsigned int u; } a; a.f = f;
    unsigned int u = a.u;
    return (unsigned short)((u + 0x7FFFu + ((u >> 16) & 1u)) >> 16);
}

__device__ __forceinline__ float bf2f(unsigned short h) {
    union { unsigned int u; float f; } a; a.u = ((unsigned int)h) << 16;
    return a.f;
}

__device__ __forceinline__ unsigned int pkbf(float a, float b) {
    return (unsigned int)f2bf(a) | ((unsigned int)f2bf(b) << 16);
}

// tanh-approx GELU; |err vs exact erf-GELU| <~ 1e-4, below bf16 rounding.
__device__ __forceinline__ float gelu_fast(float v) {
    float u = 0.7978845608f * v * (1.0f + 0.044715f * v * v);
    float e = __builtin_amdgcn_exp2f(u * 2.885390082f);      // exp(2u)
    float t = 1.0f - 2.0f * __builtin_amdgcn_rcpf(1.0f + e); // tanh(u)
    return 0.5f * v * (1.0f + t);
}

// async global->LDS, 16B per lane; LDS dst = wave-uniform base + lane*16
__device__ __forceinline__ void gl_lds16(const unsigned short* g, unsigned short* l) {
    __builtin_amdgcn_global_load_lds(
        (const __attribute__((address_space(1))) void*)g,
        (__attribute__((address_space(3))) void*)l, 16, 0, 0);
}

#define BARX() asm volatile("s_barrier" ::: "memory")
#define VMW8() asm volatile("s_waitcnt vmcnt(8)" ::: "memory")
#define VMW4() asm volatile("s_waitcnt vmcnt(4)" ::: "memory")
#define VMW0() asm volatile("s_waitcnt vmcnt(0)" ::: "memory")

// ---- fused prep: weight transpose+convert (4608) + u1c1 seed (2) + LN (8192)
__global__ __launch_bounds__(256) void prep_kernel(
    const float* __restrict__ W1, const float* __restrict__ W2,
    const float* __restrict__ W3, const float* __restrict__ W4,
    const float* __restrict__ gamma, const float* __restrict__ b1,
    const float* __restrict__ x,
    unsigned short* __restrict__ Wt1, unsigned short* __restrict__ Wt2,
    unsigned short* __restrict__ Wt3, unsigned short* __restrict__ Wt4,
    float* __restrict__ u1, float* __restrict__ c1,
    float* __restrict__ mu, float* __restrict__ rs,
    unsigned short* __restrict__ xb) {
    int b = blockIdx.x;
    if (b < 4608) {            // ---- weight convert/transpose
        const float* W; unsigned short* Wt; int K, N; const float* sc = nullptr;
        if (b < 2048)      { W = W1; Wt = Wt1; K = 1024; N = 512;  sc = gamma; }
        else if (b < 3072) { W = W2; Wt = Wt2; K = 512;  N = 512;  b -= 2048; }
        else if (b < 3584) { W = W3; Wt = Wt3; K = 512;  N = 256;  b -= 3072; }
        else               { W = W4; Wt = Wt4; K = 256;  N = 1024; b -= 3584; }
        int t = b * 256 + threadIdx.x;
        int sh = 31 - __clz(N);
        int k = t >> sh, n = t & (N - 1);
        float v = W[t];
        if (sc) v *= sc[k];
        Wt[(size_t)n * K + k] = f2bf(v);
        return;
    }
    if (b < 4610) {            // ---- u1/c1 seed (before atomic u1c1_kernel)
        int n = (b - 4608) * 256 + threadIdx.x;
        u1[n] = 0.f;
        c1[n] = b1[n];
        return;
    }
    // ---- LN row stats + xb = bf16(x)
    const int D = 1024;
    int row = (b - 4610) * 4 + (threadIdx.x >> 6);
    int lane = threadIdx.x & 63;
    const float4* xr = (const float4*)(x + (size_t)row * D);
    float s = 0.f, ss = 0.f;
#pragma unroll
    for (int i = 0; i < 4; i++) {
        float4 v = xr[lane + 64 * i];
        s  += v.x + v.y + v.z + v.w;
        ss += v.x * v.x + v.y * v.y + v.z * v.z + v.w * v.w;
        if (xb) {
            ushort4v o;
            o.x = f2bf(v.x); o.y = f2bf(v.y); o.z = f2bf(v.z); o.w = f2bf(v.w);
            *(ushort4v*)(xb + (size_t)row * D + 4 * (lane + 64 * i)) = o;
        }
    }
#pragma unroll
    for (int off = 32; off; off >>= 1) {
        s  += __shfl_xor(s, off);
        ss += __shfl_xor(ss, off);
    }
    if (lane == 0) {
        float m = s * (1.0f / 1024.0f);
        mu[row] = m;
        rs[row] = rsqrtf(ss * (1.0f / 1024.0f) - m * m + 1e-5f);
    }
}

__global__ __launch_bounds__(256) void u1c1_kernel(
    const float* __restrict__ W1, const float* __restrict__ gamma,
    const float* __restrict__ beta, float* __restrict__ u1,
    float* __restrict__ c1) {
    const int N = 512;
    __shared__ float gs[16], bs[16];
    int n = threadIdx.x;
    int k0 = blockIdx.x * 16;
    if (n < 16) { gs[n] = gamma[k0 + n]; bs[n] = beta[k0 + n]; }
    __syncthreads();
    float ua = 0.f, ca = 0.f, ub = 0.f, cb = 0.f;
#pragma unroll
    for (int i = 0; i < 16; i++) {
        float w0 = W1[(size_t)(k0 + i) * N + n];
        float w1 = W1[(size_t)(k0 + i) * N + n + 256];
        ua += gs[i] * w0; ca += bs[i] * w0;
        ub += gs[i] * w1; cb += bs[i] * w1;
    }
    atomicAdd(&u1[n], ua);       atomicAdd(&c1[n], ca);
    atomicAdd(&u1[n + 256], ub); atomicAdd(&c1[n + 256], cb);
}

// ---------------------------------------------------------------------------
// 256x256 8-wave chunk-ring GEMM (G1/G2). R18: 2-bit row-XOR granule swizzle
// (phys_g = logical_g ^ ((row>>1)&3)) on staged source + frag reads ->
// quarter-wave hits all 8 (bank-half, granule) positions 2 lanes each.
// ---------------------------------------------------------------------------
__device__ __forceinline__ void ldA8(const unsigned short* base, short8 (&a)[8]) {
#pragma unroll
    for (int mt = 0; mt < 8; mt++) a[mt] = *(const short8*)(base + mt * 512);
}
__device__ __forceinline__ void ldB2(const unsigned short* base, short8 (&bb)[2]) {
    bb[0] = *(const short8*)(base);
    bb[1] = *(const short8*)(base + 512);
}
template <int CH>
__device__ __forceinline__ void mm16(const short8 (&a)[8], const short8 (&bb)[2],
                                     floatx4 (&acc)[8][4]) {
    __builtin_amdgcn_s_setprio(1);
#pragma unroll
    for (int mt = 0; mt < 8; mt++)
#pragma unroll
        for (int nt = 0; nt < 2; nt++)
            acc[mt][CH * 2 + nt] = __builtin_amdgcn_mfma_f32_16x16x32_bf16(
                bb[nt], a[mt], acc[mt][CH * 2 + nt], 0, 0, 0);
    __builtin_amdgcn_s_setprio(0);
}

// MODE 0: steady | 1: penultimate | 2: last
template <int KLEN, int MODE>
__device__ __forceinline__ void do_tile(
    const unsigned short* aF0, const unsigned short* bF0,
    const unsigned short* aF1, const unsigned short* bF1,
    unsigned short* sA3, unsigned short* sB3,
    unsigned short* sA4, unsigned short* sB4,
    const unsigned short* gAs, const unsigned short* gBs,
    short8 (&a)[8], short8 (&bb)[2], floatx4 (&acc)[8][4]) {
    ldA8(aF0, a);
    ldB2(bF0, bb);
    if (MODE <= 1) {
        gl_lds16(gAs + 96, sA3);
        gl_lds16(gAs + 96 + (size_t)128 * KLEN, sA3 + 4096);
    }
    mm16<0>(a, bb, acc);
    BARX();
    ldB2(bF0 + 1024, bb);
    if (MODE <= 1) {
        gl_lds16(gBs + 96, sB3);
        gl_lds16(gBs + 96 + (size_t)128 * KLEN, sB3 + 4096);
    }
    mm16<1>(a, bb, acc);
    if (MODE <= 1) { VMW8(); } else { VMW0(); }
    BARX();
    ldA8(aF1, a);
    ldB2(bF1, bb);
    if (MODE == 0) {
        gl_lds16(gAs + 128, sA4);
        gl_lds16(gAs + 128 + (size_t)128 * KLEN, sA4 + 4096);
    }
    mm16<0>(a, bb, acc);
    BARX();
    ldB2(bF1 + 1024, bb);
    if (MODE == 0) {
        gl_lds16(gBs + 128, sB4);
        gl_lds16(gBs + 128 + (size_t)128 * KLEN, sB4 + 4096);
    }
    mm16<1>(a, bb, acc);
    if (MODE == 0) { VMW8(); }
    else if (MODE == 1) { VMW4(); }
    BARX();
}

template <int EPMODE, int NBN, int NT, int NOUT, int KLEN>
__global__ __launch_bounds__(512, 2) void gemm256_kernel(
    const unsigned short* __restrict__ A, const unsigned short* __restrict__ Bt,
    unsigned short* __restrict__ Out,
    const float* __restrict__ bias,
    const float* __restrict__ u1,
    const float* __restrict__ mu,
    const float* __restrict__ rs)
{
    __shared__ unsigned short lds[4][2][8192];

    const int tid  = threadIdx.x;
    const int wave = tid >> 6;
    const int lane = tid & 63;
    const int q    = lane >> 4;
    const int l16  = lane & 15;
    const int wm   = wave >> 2;
    const int wn   = wave & 3;

    const int id   = blockIdx.x;
    const int xcd  = id & 7;
    const int slot = id >> 3;
    const int m0   = (xcd + 8 * (slot / NBN)) * 256;
    const int n0   = (slot % NBN) * 256;

    // staging: thread -> row tid>>2, phys granule tid&3; SOURCE granule is
    // inverse-swizzled: sg = (tid&3) ^ ((row>>1)&3), row=tid>>2 (+128 keeps it)
    const int sg0 = (tid & 3) ^ ((tid >> 3) & 3);
    const unsigned short* gAs = A  + (size_t)(m0 + (tid >> 2)) * KLEN + sg0 * 8;
    const unsigned short* gBs = Bt + (size_t)(n0 + (tid >> 2)) * KLEN + sg0 * 8;

    const int wo = wave << 9;
    unsigned short* sA[4]; unsigned short* sB[4];
    const unsigned short* fA[4]; const unsigned short* fB[4];
    // frag reads: phys granule = q ^ ((row>>1)&3) = q ^ ((l16>>1)&3)
    const int gsw  = (q ^ ((l16 >> 1) & 3)) * 8;
    const int aoff = (wm * 128 + l16) * 32 + gsw;
    const int boff = (wn * 64 + l16) * 32 + gsw;
#pragma unroll
    for (int s = 0; s < 4; s++) {
        sA[s] = &lds[s][0][0] + wo;
        sB[s] = &lds[s][1][0] + wo;
        fA[s] = &lds[s][0][0] + aoff;
        fB[s] = &lds[s][1][0] + boff;
    }

    floatx4 acc[8][4] = {};
    short8 a[8], bb[2];

    gl_lds16(gAs,      sA[0]); gl_lds16(gAs      + (size_t)128 * KLEN, sA[0] + 4096);
    gl_lds16(gBs,      sB[0]); gl_lds16(gBs      + (size_t)128 * KLEN, sB[0] + 4096);
    gl_lds16(gAs + 32, sA[1]); gl_lds16(gAs + 32 + (size_t)128 * KLEN, sA[1] + 4096);
    gl_lds16(gBs + 32, sB[1]); gl_lds16(gBs + 32 + (size_t)128 * KLEN, sB[1] + 4096);
    gl_lds16(gAs + 64, sA[2]); gl_lds16(gAs + 64 + (size_t)128 * KLEN, sA[2] + 4096);
    gl_lds16(gBs + 64, sB[2]); gl_lds16(gBs + 64 + (size_t)128 * KLEN, sB[2] + 4096);
    VMW8();
    BARX();

    for (int t = 0; t + 2 < NT; t += 2) {
        do_tile<KLEN, 0>(fA[0], fB[0], fA[1], fB[1], sA[3], sB[3], sA[0], sB[0],
                         gAs, gBs, a, bb, acc);
        gAs += 64; gBs += 64;
        do_tile<KLEN, 0>(fA[2], fB[2], fA[3], fB[3], sA[1], sB[1], sA[2], sB[2],
                         gAs, gBs, a, bb, acc);
        gAs += 64; gBs += 64;
    }
    do_tile<KLEN, 1>(fA[0], fB[0], fA[1], fB[1], sA[3], sB[3], sA[0], sB[0],
                     gAs, gBs, a, bb, acc);
    gAs += 64; gBs += 64;
    do_tile<KLEN, 2>(fA[2], fB[2], fA[3], fB[3], sA[1], sB[1], sA[2], sB[2],
                     gAs, gBs, a, bb, acc);

    float rs8[8], mu8[8];
    if constexpr (EPMODE == 0) {
#pragma unroll
        for (int ma = 0; ma < 8; ma++) {
            const int row = m0 + wm * 128 + ma * 16 + l16;
            rs8[ma] = rs[row];
            mu8[ma] = mu[row];
        }
    }
#pragma unroll
    for (int na = 0; na < 4; na++) {
        const int nb = n0 + wn * 64 + na * 16 + q * 4;
        const float4 bv = *(const float4*)(bias + nb);
        float4 uv = {0.f, 0.f, 0.f, 0.f};
        if constexpr (EPMODE == 0) uv = *(const float4*)(u1 + nb);
#pragma unroll
        for (int ma = 0; ma < 8; ma++) {
            const int row = m0 + wm * 128 + ma * 16 + l16;
            const size_t off = (size_t)row * NOUT + nb;
            float v0 = acc[ma][na][0], v1 = acc[ma][na][1];
            float v2 = acc[ma][na][2], v3 = acc[ma][na][3];
            if constexpr (EPMODE == 0) {
                v0 = gelu_fast(rs8[ma] * (v0 - mu8[ma] * uv.x) + bv.x);
                v1 = gelu_fast(rs8[ma] * (v1 - mu8[ma] * uv.y) + bv.y);
                v2 = gelu_fast(rs8[ma] * (v2 - mu8[ma] * uv.z) + bv.z);
                v3 = gelu_fast(rs8[ma] * (v3 - mu8[ma] * uv.w) + bv.w);
            } else {
                v0 = gelu_fast(v0 + bv.x);
                v1 = gelu_fast(v1 + bv.y);
                v2 = gelu_fast(v2 + bv.z);
                v3 = gelu_fast(v3 + bv.w);
            }
            uint2v o; o.x = pkbf(v0, v1); o.y = pkbf(v2, v3);
            *(uint2v*)(Out + off) = o;
        }
    }
}

// ---- 128x128 2-phase GEMM (G3/G4), measured at R7/R9/R11 ----------------
template <int EPMODE, bool AF32, int NBN, int NT_, int KT>
__global__ __launch_bounds__(256) void gemm_kernel(
    const void* __restrict__ Aptr, const unsigned short* __restrict__ Bt,
    void* __restrict__ Out,
    const float* __restrict__ bias,
    const float* __restrict__ u1,
    const float* __restrict__ mu,
    const float* __restrict__ rs,
    const void* __restrict__ resid)
{
    constexpr int BM = 128, BN = 128, BK = 64;
    constexpr int N = NT_, K = KT;
    __shared__ unsigned short As[BM][BK];
    __shared__ unsigned short Bs[BN][BK];

    const int tid  = threadIdx.x;
    const int wave = tid >> 6;
    const int lane = tid & 63;
    const int q    = lane >> 4;
    const int l16  = lane & 15;
    const int wm   = wave & 1;
    const int wn   = wave >> 1;

    const int id   = blockIdx.x;
    const int xcd  = id & 7;
    const int slot = id >> 3;
    const int m0   = (xcd + 8 * (slot / NBN)) * BM;
    const int n0   = (slot % NBN) * BN;

    const int sr  = tid >> 3;
    const int sc  = tid & 7;
    const int sg  = sc ^ (sr & 7);
    unsigned short* lA = &As[0][0] + (wave << 9);
    unsigned short* lB = &Bs[0][0] + (wave << 9);
    const unsigned short* gb0 = Bt + (size_t)(n0 + sr) * K + sg * 8;
    const unsigned short* ga0 = nullptr;
    if (!AF32) ga0 = (const unsigned short*)Aptr + (size_t)(m0 + sr) * K + sg * 8;

    floatx4 acc[4][4] = {};

#pragma unroll
    for (int k0 = 0; k0 < K; k0 += BK) {
        if (AF32) {
            const float* A = (const float*)Aptr;
            int c = tid & 15, r0 = tid >> 4;
#pragma unroll
            for (int i = 0; i < 8; i++) {
                int r = r0 + 16 * i;
                float4 v = *(const float4*)(A + (size_t)(m0 + r) * K + k0 + c * 4);
                ushort4v o;
                o.x = f2bf(v.x); o.y = f2bf(v.y);
                o.z = f2bf(v.z); o.w = f2bf(v.w);
                int idx = r * 64 + (((c >> 1) ^ (r & 7)) << 3) + ((c & 1) << 2);
                *(ushort4v*)(&As[0][0] + idx) = o;
            }
        } else {
#pragma unroll
            for (int c = 0; c < 4; c++)
                gl_lds16(ga0 + k0 + (size_t)(32 * c) * K, lA + c * 2048);
        }
#pragma unroll
        for (int c = 0; c < 4; c++)
            gl_lds16(gb0 + k0 + (size_t)(32 * c) * K, lB + c * 2048);
        __syncthreads();

#pragma unroll
        for (int kk = 0; kk < 2; kk++) {
            const int gsw = ((kk * 4 + q) ^ (l16 & 7)) * 8;
            short8 a[4], b[4];
#pragma unroll
            for (int mt = 0; mt < 4; mt++)
                a[mt] = *(const short8*)(&As[0][0] + (wm * 64 + mt * 16 + l16) * 64 + gsw);
#pragma unroll
            for (int nt = 0; nt < 4; nt++)
                b[nt] = *(const short8*)(&Bs[0][0] + (wn * 64 + nt * 16 + l16) * 64 + gsw);
#pragma unroll
            for (int nt = 0; nt < 4; nt++)
#pragma unroll
                for (int mt = 0; mt < 4; mt++)
                    acc[nt][mt] = __builtin_amdgcn_mfma_f32_16x16x32_bf16(
                        b[nt], a[mt], acc[nt][mt], 0, 0, 0);
        }
        __syncthreads();
    }

    float rs4[4], mu4[4];
    if constexpr (EPMODE == 0) {
#pragma unroll
        for (int mt = 0; mt < 4; mt++) {
            const int row = m0 + wm * 64 + mt * 16 + l16;
            rs4[mt] = rs[row];
            mu4[mt] = mu[row];
        }
    }
#pragma unroll
    for (int nt = 0; nt < 4; nt++) {
        const int nbase = n0 + wn * 64 + nt * 16 + q * 4;
        const float4 bv = *(const float4*)(bias + nbase);
        float4 uv = {0.f, 0.f, 0.f, 0.f};
        if constexpr (EPMODE == 0) uv = *(const float4*)(u1 + nbase);
#pragma unroll
        for (int mt = 0; mt < 4; mt++) {
            const int row = m0 + wm * 64 + mt * 16 + l16;
            const size_t off = (size_t)row * N + nbase;
            float v0 = acc[nt][mt][0], v1 = acc[nt][mt][1];
            float v2 = acc[nt][mt][2], v3 = acc[nt][mt][3];
            if constexpr (EPMODE == 0) {
                v0 = gelu_fast(rs4[mt] * (v0 - mu4[mt] * uv.x) + bv.x);
                v1 = gelu_fast(rs4[mt] * (v1 - mu4[mt] * uv.y) + bv.y);
                v2 = gelu_fast(rs4[mt] * (v2 - mu4[mt] * uv.z) + bv.z);
                v3 = gelu_fast(rs4[mt] * (v3 - mu4[mt] * uv.w) + bv.w);
                uint2v o; o.x = pkbf(v0, v1); o.y = pkbf(v2, v3);
                *(uint2v*)((unsigned short*)Out + off) = o;
            } else if constexpr (EPMODE == 1) {
                v0 = gelu_fast(v0 + bv.x);
                v1 = gelu_fast(v1 + bv.y);
                v2 = gelu_fast(v2 + bv.z);
                v3 = gelu_fast(v3 + bv.w);
                uint2v o; o.x = pkbf(v0, v1); o.y = pkbf(v2, v3);
                *(uint2v*)((unsigned short*)Out + off) = o;
            } else if constexpr (EPMODE == 2) {
                const float4 rv = *(const float4*)((const float*)resid + off);
                float4 o;
                o.x = v0 + bv.x + rv.x;
                o.y = v1 + bv.y + rv.y;
                o.z = v2 + bv.z + rv.z;
                o.w = v3 + bv.w + rv.w;
                *(float4*)((float*)Out + off) = o;
            } else {
                const ushort4v rv =
                    *(const ushort4v*)((const unsigned short*)resid + off);
                float4 o;
                o.x = v0 + bv.x + bf2f(rv.x);
                o.y = v1 + bv.y + bf2f(rv.y);
                o.z = v2 + bv.z + bf2f(rv.z);
                o.w = v3 + bv.w + bf2f(rv.w);
                *(float4*)((float*)Out + off) = o;
            }
        }
    }
}

extern "C" void kernel_launch(void* const* d_in, const int* in_sizes, int n_in,
                              void* d_out, int out_size, void* d_ws, size_t ws_size,
                              hipStream_t stream) {
    const float* x     = (const float*)d_in[0];
    const float* gamma = (const float*)d_in[1];
    const float* beta  = (const float*)d_in[2];
    const float* W1    = (const float*)d_in[3];
    const float* b1    = (const float*)d_in[4];
    const float* W2    = (const float*)d_in[5];
    const float* b2    = (const float*)d_in[6];
    const float* W3    = (const float*)d_in[7];
    const float* b3    = (const float*)d_in[8];
    const float* W4    = (const float*)d_in[9];
    const float* b4    = (const float*)d_in[10];
    float* out = (float*)d_out;

    const int D = 1024, H1 = 512, H2 = 512;
    const int M = in_sizes[0] / D;   // 32768

    char* ws = (char*)d_ws;
    unsigned short* Wt1 = (unsigned short*)(ws + 0);
    unsigned short* Wt2 = (unsigned short*)(ws + 1048576);
    unsigned short* Wt3 = (unsigned short*)(ws + 1572864);
    unsigned short* Wt4 = (unsigned short*)(ws + 1835008);
    float* u1           = (float*)(ws + 2359296);
    float* c1           = (float*)(ws + 2361344);
    float* muv          = (float*)(ws + 2363392);
    float* rsv          = (float*)(ws + 2494464);
    unsigned short* h1  = (unsigned short*)(ws + 2625536);    // M x 512 bf16
    unsigned short* h2  = (unsigned short*)(ws + 36179968);   // M x 512 bf16
    unsigned short* h3  = h1;                                 // h1 dead after G2
    size_t base_end     = 36179968 + (size_t)M * H2 * 2;
    unsigned short* xb  = (unsigned short*)(ws + base_end);
    bool use_xb = (ws_size >= base_end + (size_t)M * D * 2);

    const int NBM = M / 128;   // 256

    // 1) prep: weight convert + u1c1 seed + LN stats (+xb)
    prep_kernel<<<4610 + M / 4, 256, 0, stream>>>(
        W1, W2, W3, W4, gamma, b1, x, Wt1, Wt2, Wt3, Wt4,
        u1, c1, muv, rsv, use_xb ? xb : nullptr);
    // 2) u1/c1 accumulation
    u1c1_kernel<<<D / 16, 256, 0, stream>>>(W1, gamma, beta, u1, c1);
    // 3) G1
    if (use_xb) {
        gemm256_kernel<0, 2, 16, 512, 1024><<<(M / 256) * 2, 512, 0, stream>>>(
            xb, Wt1, h1, c1, u1, muv, rsv);
    } else {
        gemm_kernel<0, true, 4, 512, 1024><<<4 * NBM, 256, 0, stream>>>(
            x, Wt1, h1, c1, u1, muv, rsv, nullptr);
    }
    // 4) G2
    gemm256_kernel<1, 2, 8, 512, 512><<<(M / 256) * 2, 512, 0, stream>>>(
        h1, Wt2, h2, b2, nullptr, nullptr, nullptr);
    // 5) G3
    gemm_kernel<1, false, 2, 256, 512><<<2 * NBM, 256, 0, stream>>>(
        h2, Wt3, h3, b3, nullptr, nullptr, nullptr, nullptr);
    // 6) G4 (+residual)
    if (use_xb) {
        gemm_kernel<3, false, 8, 1024, 256><<<8 * NBM, 256, 0, stream>>>(
            h3, Wt4, out, b4, nullptr, nullptr, nullptr, xb);
    } else {
        gemm_kernel<2, false, 8, 1024, 256><<<8 * NBM, 256, 0, stream>>>(
            h3, Wt4, out, b4, nullptr, nullptr, nullptr, x);
    }
}